// Round 1
// baseline (54.291 us; speedup 1.0000x reference)
//
#include <hip/hip_runtime.h>

// RoI max-pooling, matching torchvision roi_pool / the JAX reference:
//   coords = trunc(roi * 0.0625) clipped to [0, 37]
//   adaptive bins: s = lo + floor(p*len/7), e = lo + ceil((p+1)*len/7)
//   out[n,c,p,q] = max over bin rectangle of features[b,c,:,:]
//
// Shapes: features [4,256,38,38] f32, rois [512,5] f32, out [512,256,7,7] f32.

#define NROIS 512
#define CCH   256
#define FH    38
#define FW    38
#define PH    7
#define PW    7
#define SCALE 0.0625f

__global__ __launch_bounds__(256) void roipool_kernel(
    const float* __restrict__ feat,
    const float* __restrict__ rois,
    float* __restrict__ out)
{
    int idx = blockIdx.x * blockDim.x + threadIdx.x;
    // idx = ((n*C + c)*PH + p)*PW + q
    int q = idx % PW;
    int t = idx / PW;
    int p = t % PH;
    t /= PH;
    int c = t % CCH;
    int n = t / CCH;

    const float* r = rois + n * 5;
    int b  = (int)r[0];
    int x1 = (int)truncf(r[1] * SCALE);
    int y1 = (int)truncf(r[2] * SCALE);
    int x2 = (int)truncf(r[3] * SCALE);
    int y2 = (int)truncf(r[4] * SCALE);
    x1 = min(max(x1, 0), FW - 1);
    y1 = min(max(y1, 0), FH - 1);
    x2 = min(max(x2, 0), FW - 1);
    y2 = min(max(y2, 0), FH - 1);
    int hh = y2 - y1 + 1;   // >= 1
    int ww = x2 - x1 + 1;   // >= 1

    int ys = y1 + (p * hh) / PH;
    int ye = y1 + ((p + 1) * hh + PH - 1) / PH;   // ceil
    int xs = x1 + (q * ww) / PW;
    int xe = x1 + ((q + 1) * ww + PW - 1) / PW;   // ceil

    const float* base = feat + ((size_t)b * CCH + c) * (FH * FW);
    float m = -3.402823466e+38f;
    for (int y = ys; y < ye; ++y) {
        const float* row = base + (size_t)y * FW;
        for (int x = xs; x < xe; ++x) {
            m = fmaxf(m, row[x]);
        }
    }
    out[idx] = m;
}

extern "C" void kernel_launch(void* const* d_in, const int* in_sizes, int n_in,
                              void* d_out, int out_size, void* d_ws, size_t ws_size,
                              hipStream_t stream) {
    const float* feat = (const float*)d_in[0];
    const float* rois = (const float*)d_in[1];
    float* out = (float*)d_out;

    const int total = NROIS * CCH * PH * PW;          // 6,422,528
    const int block = 256;
    const int grid = (total + block - 1) / block;      // 25,088
    roipool_kernel<<<grid, block, 0, stream>>>(feat, rois, out);
}